// Round 21
// baseline (115.124 us; speedup 1.0000x reference)
//
#include <hip/hip_runtime.h>
#include <math.h>

#define N_   4
#define C_   128
#define H_   128
#define W_   128
#define HW_  16384
#define SCALE_ 0.17677669529663687f   // 32^-0.5

typedef unsigned short u16;
typedef unsigned int   u32;
typedef __bf16 bf16x8 __attribute__((ext_vector_type(8)));
typedef float  f32x4  __attribute__((ext_vector_type(4)));

#define MFMA(a, b, c) __builtin_amdgcn_mfma_f32_16x16x32_bf16((a), (b), (c), 0, 0, 0)

// ---- ws float offsets -------------------------------------------------------
#define QB_OFF   0            // 4,194,304 floats (8,388,608 u16 bf16 q)
#define Y_OFF    4194304      // y as bf16: 1,638,400 u16
#define KB_OFF   5832704      //   409,600 floats (819,200 u16 bf16 K)
#define VT_OFF   6242304      //   409,600 floats (819,200 u16 bf16 V^T)
#define PART_OFF 6651904      // 8,388,608 floats:
                              //   [0..4.19M): bf16 partials (8.39M u16); cbuf16 aliases
                              //   [4.19M..8.39M): inphT (8.39M u16, [token][c])
#define WSP_OFF  15040512     //   868,352 floats (2 x 868,352 u16 hi+lo)
#define INH_OFF  15908864     // 4,194,304 floats (8,388,608 u16 bf16 input [c][t])
#define SCB_OFF  20103168     //       256 floats (S[128], cb[128])
// total 20,103,424 floats = 80.4 MB

// split-weight region offsets (u16 units, within hi or lo half)
// OQW/OPW/OKV in MFMA FRAGMENT ORDER; conv heads (OS1..OS4) in per-seg
// FRAGMENT ORDER: dst = base + seg*16384 + ((ct*8+kt)*64 + lane)*8 + e
#define OQW 0
#define OPW 16384
#define OS1 32768
#define OS2 557056
#define OS3 688128
#define OS4 819200
#define OKV 851968
#define TOTW 868352

#define GS  520    // A-LDS kgroup stride (lnkv), u16

// ---------------------------------------------------------------------------
__device__ __forceinline__ u16 f2bf_rne(float x) {
  unsigned u = __float_as_uint(x);
  return (u16)((u + 0x7FFFu + ((u >> 16) & 1u)) >> 16);
}
__device__ __forceinline__ float bf2f(u16 x) {
  return __uint_as_float((u32)x << 16);
}
__device__ __forceinline__ void split2(float v, u16& h, u16& l) {
  unsigned u = __float_as_uint(v);
  unsigned hb = (u + 0x7FFFu + ((u >> 16) & 1u)) & 0xFFFF0000u;
  h = (u16)(hb >> 16);
  float lf = v - __uint_as_float(hb);
  l = f2bf_rne(lf);
}

// ---------------------------------------------------------------------------
// prep: [bid<1024]       input fp32 tile -> inph bf16 [c][t] AND inphT [t][c]
//       [1024..+3392)    weights fp32 -> bf16 hi/lo, fragment orders
//       [last block]     S[o], cb[o]
// ---------------------------------------------------------------------------
__global__ __launch_bounds__(256) void prep_kernel(
    const float* __restrict__ inp, const float* __restrict__ qw,
    const float* __restrict__ pw, const float* __restrict__ s1,
    const float* __restrict__ s2, const float* __restrict__ s3,
    const float* __restrict__ s4, const float* __restrict__ kv1,
    const float* __restrict__ kv2, const float* __restrict__ kv3,
    const float* __restrict__ kv4, const float* __restrict__ nw,
    const float* __restrict__ nb, const float* __restrict__ qb,
    u16* __restrict__ hi, u16* __restrict__ lo, u16* __restrict__ inph,
    u16* __restrict__ inphT, float* __restrict__ scb) {
  __shared__ float tls[64 * 133];
  int bid = blockIdx.x, tid = threadIdx.x;
  if (bid < 1024) {
    int n = bid >> 8, t0 = (bid & 255) * 64;
    const float* xb = inp + (size_t)n * C_ * HW_ + t0;
    u16* ihb = inph + (size_t)n * C_ * HW_ + t0;
    #pragma unroll
    for (int it = 0; it < 8; ++it) {
      int u = it * 256 + tid;                 // 2048 float4 units
      int c = u >> 4, tokg = u & 15;
      float4 v = *(const float4*)&xb[(size_t)c * HW_ + tokg * 4];
      ushort4 h4;
      h4.x = f2bf_rne(v.x); h4.y = f2bf_rne(v.y);
      h4.z = f2bf_rne(v.z); h4.w = f2bf_rne(v.w);
      *(ushort4*)&ihb[(size_t)c * HW_ + tokg * 4] = h4;
      tls[(tokg * 4 + 0) * 133 + c] = v.x;
      tls[(tokg * 4 + 1) * 133 + c] = v.y;
      tls[(tokg * 4 + 2) * 133 + c] = v.z;
      tls[(tokg * 4 + 3) * 133 + c] = v.w;
    }
    __syncthreads();
    #pragma unroll
    for (int it = 0; it < 4; ++it) {
      int u = it * 256 + tid;                 // 1024 units
      int tok = u >> 4, cg = u & 15;
      union { u16 e[8]; uint4 q; } cv;
      #pragma unroll
      for (int e = 0; e < 8; ++e)
        cv.e[e] = f2bf_rne(tls[tok * 133 + cg * 8 + e]);
      *(uint4*)&inphT[((size_t)(n * HW_ + t0 + tok)) * 128 + cg * 8] = cv.q;
    }
  } else if (bid < 1024 + TOTW / 256) {
    int idx = (bid - 1024) * 256 + tid;       // < TOTW (source-linear)
    const float* src; int off;
    float mul = 1.0f;
    int dst = idx;
    if (idx < OPW) {                       // qw: 128x128 -> frag order
      src = qw; off = idx; mul = nw[idx & 127];
      int o = idx >> 7, k = idx & 127;
      int ct = o >> 4, r = o & 15, kk = k >> 5, g = (k >> 3) & 3, e = k & 7;
      dst = OQW + ((ct * 4 + kk) * 64 + g * 16 + r) * 8 + e;
    } else if (idx < OS1) {                // pw: 128x128 -> frag order
      src = pw; off = idx - OPW;
      int o = off >> 7, k = off & 127;
      int ct = o >> 4, r = o & 15, kk = k >> 5, g = (k >> 3) & 3, e = k & 7;
      dst = OPW + ((ct * 4 + kk) * 64 + g * 16 + r) * 8 + e;
    } else if (idx < OS2) {                // conv1: 64x8192 -> per-seg frag
      src = s1; off = idx - OS1;
      int o = off >> 13, k = off & 8191;
      int seg = k >> 8, kt = (k >> 5) & 7, g = (k >> 3) & 3, e = k & 7;
      dst = OS1 + seg * 16384 +
            (((o >> 4) * 8 + kt) * 64 + g * 16 + (o & 15)) * 8 + e;
    } else if (idx < OS3) {                // conv2: 64x2048 -> per-seg frag
      src = s2; off = idx - OS2;
      int o = off >> 11, k = off & 2047;
      int seg = k >> 8, kt = (k >> 5) & 7, g = (k >> 3) & 3, e = k & 7;
      dst = OS2 + seg * 16384 +
            (((o >> 4) * 8 + kt) * 64 + g * 16 + (o & 15)) * 8 + e;
    } else if (idx < OS4) {                // conv3: 64x2048 -> per-seg frag
      src = s3; off = idx - OS3;
      int o = off >> 11, k = off & 2047;
      int seg = k >> 8, kt = (k >> 5) & 7, g = (k >> 3) & 3, e = k & 7;
      dst = OS3 + seg * 16384 +
            (((o >> 4) * 8 + kt) * 64 + g * 16 + (o & 15)) * 8 + e;
    } else if (idx < OKV) {                // conv4: 64x512 -> per-seg frag
      src = s4; off = idx - OS4;
      int o = off >> 9, k = off & 511;
      int seg = k >> 8, kt = (k >> 5) & 7, g = (k >> 3) & 3, e = k & 7;
      dst = OS4 + seg * 16384 +
            (((o >> 4) * 8 + kt) * 64 + g * 16 + (o & 15)) * 8 + e;
    } else {                               // kv: 4 x 64x64 -> frag order
      int j = idx - OKV;
      int h = j >> 12; int o2 = j & 4095;
      src = (h == 0) ? kv1 : (h == 1) ? kv2 : (h == 2) ? kv3 : kv4;
      off = o2;
      int o = o2 >> 6, k = o2 & 63;
      int ct = o >> 4, r = o & 15, kk = k >> 5, g = (k >> 3) & 3, e = k & 7;
      dst = OKV + h * 4096 + ((ct * 2 + kk) * 64 + g * 16 + r) * 8 + e;
    }
    u16 h, l; split2(src[off] * mul, h, l);
    hi[dst] = h; lo[dst] = l;
  } else {
    int o = tid;
    if (o < 128) {
      float S = 0.f, cbv = qb[o];
      const float* wr = qw + o * 128;
      for (int c = 0; c < 128; ++c) {
        float w = wr[c];
        S   += w * nw[c];
        cbv += w * nb[c];
      }
      scb[o]       = S;
      scb[128 + o] = cbv;
    }
  }
}

// ---------------------------------------------------------------------------
// LN-folded Q projection, contiguous A-frags from inphT, FRAG-ORDER B loads
// ---------------------------------------------------------------------------
__device__ __forceinline__ void lnqT_body(
    int bid, const u16* __restrict__ inphT, const u16* __restrict__ wh,
    const u16* __restrict__ wl, const float* __restrict__ scb,
    u16* __restrict__ q) {
  int tid = threadIdx.x;
  int n = bid >> 8, t0 = (bid & 255) * 64;
  int wid = tid >> 6, lane = tid & 63, r = lane & 15, g = lane >> 4;
  const u16* xr = inphT + (size_t)(n * HW_ + t0 + wid * 16 + r) * 128 + g * 8;

  bf16x8 af[4];
  float s = 0.f, s2 = 0.f;
  #pragma unroll
  for (int kk = 0; kk < 4; ++kk) {
    union { uint4 u; u16 e[8]; bf16x8 b; } cv;
    cv.u = *(const uint4*)&xr[kk * 32];
    #pragma unroll
    for (int e = 0; e < 8; ++e) { float f = bf2f(cv.e[e]); s += f; s2 += f * f; }
    af[kk] = cv.b;
  }
  s  += __shfl_xor(s, 16, 64);  s  += __shfl_xor(s, 32, 64);
  s2 += __shfl_xor(s2, 16, 64); s2 += __shfl_xor(s2, 32, 64);
  float mu = s * (1.0f / 128.0f);
  float var = s2 * (1.0f / 128.0f) - mu * mu;
  float rs = rsqrtf(var + 1e-5f);

  int fl8 = lane * 8;                      // frag-order per-lane offset
  f32x4 acc[8] = {};
  #pragma unroll
  for (int kk = 0; kk < 4; ++kk) {
    #pragma unroll
    for (int ct = 0; ct < 8; ++ct) {
      int fo = (ct * 4 + kk) * 512 + fl8;
      bf16x8 bh = *(const bf16x8*)&wh[fo];
      bf16x8 bl = *(const bf16x8*)&wl[fo];
      acc[ct] = MFMA(af[kk], bh, acc[ct]);
      acc[ct] = MFMA(af[kk], bl, acc[ct]);
    }
  }
  #pragma unroll
  for (int reg = 0; reg < 4; ++reg) {
    float mur = __shfl(mu, g * 4 + reg, 64);
    float rsr = __shfl(rs, g * 4 + reg, 64);
    int row = wid * 16 + g * 4 + reg;
    #pragma unroll
    for (int ct = 0; ct < 8; ++ct) {
      int col = ct * 16 + r;
      float val = rsr * (acc[ct][reg] - mur * scb[col]) + scb[128 + col];
      q[((size_t)n * HW_ + t0 + row) * 128 + col] = f2bf_rne(val);
    }
  }
}

// ---------------------------------------------------------------------------
// conv-as-GEMM v7: BM=128, KSEG=256 (NT=8). NO LDS, NO barriers — A-frags
// gathered direct, B-frags from per-seg FRAG-ORDER global (L2-hot, coalesced).
// Partials stored BF16.
// ---------------------------------------------------------------------------
template <int P, int NW, int SEG>
__device__ __forceinline__ void conv_body(
    int mblk, int seg, const u16* __restrict__ inph,
    const u16* __restrict__ wh, u16* __restrict__ dst) {
  constexpr int K    = 128 * P * P;
  constexpr int KSEG = K / SEG;              // 256 everywhere
  constexpr int NT   = KSEG / 32;            // 8
  constexpr int HWIN = H_ / NW;
  constexpr int G    = HWIN / P;
  constexpr int L    = G * G;
  constexpr int M    = 4 * NW * NW * L;
  constexpr int LGL  = (L == 256) ? 8 : 6;
  constexpr int LGG  = (G == 16) ? 4 : 3;
  constexpr int LGNW = (NW == 8) ? 3 : (NW == 4) ? 2 : (NW == 2) ? 1 : 0;
  constexpr int LGP  = (P == 8) ? 3 : (P == 4) ? 2 : 1;
  constexpr int LGP2 = 2 * LGP;
  int tid = threadIdx.x, wid = tid >> 6, lane = tid & 63;
  int r = lane & 15, g = lane >> 4;
  int t0 = mblk * 128;
  int kbase = seg * KSEG;

  size_t rbase[2];
  #pragma unroll
  for (int mrep = 0; mrep < 2; ++mrep) {
    int tglob = t0 + wid * 32 + mrep * 16 + r;
    int bwin = tglob >> LGL;
    int loc  = tglob & (L - 1);
    int n    = bwin >> (2 * LGNW);
    int wrem = bwin & (NW * NW - 1);
    int wy = wrem >> LGNW, wx = wrem & (NW - 1);
    int oh = loc >> LGG,   ow = loc & (G - 1);
    rbase[mrep] = (size_t)n * C_ * HW_ + (size_t)(wy * HWIN + oh * P) * W_ +
                  wx * HWIN + ow * P;
  }
  // per-seg frag-order weight base (lane-contiguous 1KB per frag)
  const u16* wf = wh + (size_t)seg * 16384 + (size_t)lane * 8;

  f32x4 acc[2][4] = {};

  #pragma unroll
  for (int kt = 0; kt < NT; ++kt) {
    int k0 = kbase + kt * 32 + g * 8;
    int ci = k0 >> LGP2;
    int wp = k0 & (P * P - 1);
    union { uint4 u; bf16x8 b; } a0, a1;
    if constexpr (P == 8) {
      size_t koff = (size_t)ci * HW_ + (wp >> 3) * W_;
      a0.u = *(const uint4*)&inph[rbase[0] + koff];
      a1.u = *(const uint4*)&inph[rbase[1] + koff];
    } else if constexpr (P == 4) {
      int kh = wp >> 2;
      size_t b0 = rbase[0] + (size_t)ci * HW_;
      size_t b1 = rbase[1] + (size_t)ci * HW_;
      uint2 l0 = *(const uint2*)&inph[b0 + kh * W_];
      uint2 h0 = *(const uint2*)&inph[b0 + (kh + 1) * W_];
      uint2 l1 = *(const uint2*)&inph[b1 + kh * W_];
      uint2 h1 = *(const uint2*)&inph[b1 + (kh + 1) * W_];
      a0.u = make_uint4(l0.x, l0.y, h0.x, h0.y);
      a1.u = make_uint4(l1.x, l1.y, h1.x, h1.y);
    } else {  // P == 2
      size_t b0 = rbase[0] + (size_t)ci * HW_;
      size_t b1 = rbase[1] + (size_t)ci * HW_;
      a0.u = make_uint4(*(const u32*)&inph[b0], *(const u32*)&inph[b0 + W_],
                        *(const u32*)&inph[b0 + HW_], *(const u32*)&inph[b0 + HW_ + W_]);
      a1.u = make_uint4(*(const u32*)&inph[b1], *(const u32*)&inph[b1 + W_],
                        *(const u32*)&inph[b1 + HW_], *(const u32*)&inph[b1 + HW_ + W_]);
    }
    #pragma unroll
    for (int ct = 0; ct < 4; ++ct) {
      bf16x8 bh = *(const bf16x8*)&wf[(ct * 8 + kt) * 512];
      acc[0][ct] = MFMA(a0.b, bh, acc[0][ct]);
      acc[1][ct] = MFMA(a1.b, bh, acc[1][ct]);
    }
  }
  #pragma unroll
  for (int mrep = 0; mrep < 2; ++mrep) {
    #pragma unroll
    for (int ct = 0; ct < 4; ++ct) {
      int o = ct * 16 + r;
      #pragma unroll
      for (int reg = 0; reg < 4; ++reg) {
        int row = t0 + wid * 32 + mrep * 16 + g * 4 + reg;
        dst[((size_t)seg * M + row) * 64 + o] = f2bf_rne(acc[mrep][ct][reg]);
      }
    }
  }
}

// ---------------------------------------------------------------------------
// merged: [bid<1024] convs (no LDS, no barriers) ; [bid>=1024] LN-folded Q
// ---------------------------------------------------------------------------
__global__ __launch_bounds__(256) void convlnq_kernel(
    const u16* __restrict__ inph, const u16* __restrict__ inphT,
    const u16* __restrict__ whi, const u16* __restrict__ wlo,
    const float* __restrict__ scb, u16* __restrict__ part,
    u16* __restrict__ q) {
  int bid = blockIdx.x;
  if (bid < 256) {            // head1: 8 mblk x 32 seg
    conv_body<8, 1, 32>(bid >> 5, bid & 31, inph, whi + OS1, part);
  } else if (bid < 512) {     // head2: 32 mblk x 8 seg
    int lb = bid - 256;
    conv_body<4, 2, 8>(lb >> 3, lb & 7, inph, whi + OS2, part + 2097152);
  } else if (bid < 768) {     // head3: 32 mblk x 8 seg
    int lb = bid - 512;
    conv_body<4, 4, 8>(lb >> 3, lb & 7, inph, whi + OS3, part + 4194304);
  } else if (bid < 1024) {    // head4: 128 mblk x 2 seg
    int lb = bid - 768;
    conv_body<2, 8, 2>(lb >> 1, lb & 1, inph, whi + OS4, part + 6291456);
  } else {                    // lnq: 1024 blocks
    lnqT_body(bid - 1024, inphT, whi + OQW, wlo + OQW, scb, q);
  }
}

// reduce bf16 K-split partials + conv bias, all heads -> y bf16 (25600 tokens)
__global__ __launch_bounds__(256) void reduce_kernel(
    const u16* __restrict__ part, const float* __restrict__ b1,
    const float* __restrict__ b2, const float* __restrict__ b3,
    const float* __restrict__ b4, u16* __restrict__ y) {
  int idx = blockIdx.x * 256 + threadIdx.x;   // grid exactly 1,638,400/256=6400
  int tg = idx >> 6, o = idx & 63;
  float s;
  if (tg < 1024) {
    s = b1[o];
    #pragma unroll
    for (int sg = 0; sg < 32; ++sg)
      s += bf2f(part[((size_t)sg * 1024 + tg) * 64 + o]);
  } else if (tg < 5120) {
    int t = tg - 1024;
    const u16* p2 = part + 2097152;
    s = b2[o];
    #pragma unroll
    for (int sg = 0; sg < 8; ++sg)
      s += bf2f(p2[((size_t)sg * 4096 + t) * 64 + o]);
  } else if (tg < 9216) {
    int t = tg - 5120;
    const u16* p3 = part + 4194304;
    s = b3[o];
    #pragma unroll
    for (int sg = 0; sg < 8; ++sg)
      s += bf2f(p3[((size_t)sg * 4096 + t) * 64 + o]);
  } else {
    int t = tg - 9216;
    const u16* p4 = part + 6291456;
    s = b4[o] + bf2f(p4[(size_t)t * 64 + o]) +
        bf2f(p4[((size_t)16384 + t) * 64 + o]);
  }
  y[(size_t)tg * 64 + o] = f2bf_rne(s);
}

// ---------------------------------------------------------------------------
// fused LN(64) + exact GELU + KV projection (MFMA, FRAG-ORDER B, bf16 y)
// ---------------------------------------------------------------------------
struct LnkvArgs { const float* lnw[4]; const float* lnb[4]; const float* kvb[4]; };

__global__ __launch_bounds__(256) void lnkv_mfma_kernel(
    const u16* __restrict__ y, const u16* __restrict__ kvwh,
    const u16* __restrict__ kvwl, LnkvArgs a,
    u16* __restrict__ kb, u16* __restrict__ vbT) {
  __shared__ float ych[64 * 65];
  __shared__ __align__(16) u16 ash[8 * GS];
  __shared__ __align__(16) u16 asl[8 * GS];
  int bid = blockIdx.x, tid = threadIdx.x;
  int tb = bid * 64;
  int h  = (tb < 1024) ? 0 : (tb < 5120) ? 1 : (tb < 9216) ? 2 : 3;
  int hb = (h == 0) ? 0 : (h == 1) ? 1024 : (h == 2) ? 5120 : 9216;
  #pragma unroll
  for (int it = 0; it < 2; ++it) {
    int i8 = it * 256 + tid;            // 512 uint4 units
    int row = i8 >> 3, cg = i8 & 7;
    union { uint4 u; u16 e[8]; } cv;
    cv.u = *(const uint4*)&y[(size_t)(tb + row) * 64 + cg * 8];
    #pragma unroll
    for (int e = 0; e < 8; ++e)
      ych[row * 65 + cg * 8 + e] = bf2f(cv.e[e]);
  }
  __syncthreads();
  {
    int tt = tid >> 2, p = tid & 3;
    const float* xr = &ych[tt * 65 + p * 16];
    float s = 0.f, s2 = 0.f;
    #pragma unroll
    for (int i = 0; i < 16; ++i) { float v = xr[i]; s += v; s2 += v * v; }
    s  += __shfl_xor(s, 1, 64);  s  += __shfl_xor(s, 2, 64);
    s2 += __shfl_xor(s2, 1, 64); s2 += __shfl_xor(s2, 2, 64);
    float mean = s * (1.0f / 64.0f);
    float var  = s2 * (1.0f / 64.0f) - mean * mean;
    float rstd = rsqrtf(var + 1e-5f);
    const float* lnw = a.lnw[h];
    const float* lnb = a.lnb[h];
    #pragma unroll
    for (int i = 0; i < 16; ++i) {
      int ch = p * 16 + i;
      float xn = (xr[i] - mean) * rstd * lnw[ch] + lnb[ch];
      float gg = 0.5f * xn * (1.0f + erff(xn * 0.70710678118654752f));
      u16 hh, ll; split2(gg, hh, ll);
      int o = (ch >> 3) * GS + tt * 8 + (ch & 7);
      ash[o] = hh; asl[o] = ll;
    }
  }
  __syncthreads();
  int wid = tid >> 6, lane = tid & 63, r = lane & 15, g = lane >> 4;
  const u16* wbh = kvwh + h * 4096;
  const u16* wbl = kvwl + h * 4096;
  int fl8 = lane * 8;
  f32x4 acc[4] = {};
  #pragma unroll
  for (int kk = 0; kk < 2; ++kk) {
    bf16x8 ah = *(const bf16x8*)&ash[(kk * 4 + g) * GS + (wid * 16 + r) * 8];
    bf16x8 al = *(const bf16x8*)&asl[(kk * 4 + g) * GS + (wid * 16 + r) * 8];
    #pragma unroll
    for (int ct = 0; ct < 4; ++ct) {
      int fo = (ct * 2 + kk) * 512 + fl8;
      bf16x8 bh = *(const bf16x8*)&wbh[fo];
      bf16x8 bl = *(const bf16x8*)&wbl[fo];
      acc[ct] = MFMA(ah, bh, acc[ct]);
      acc[ct] = MFMA(ah, bl, acc[ct]);
      acc[ct] = MFMA(al, bh, acc[ct]);
    }
  }
  const float* kvb = a.kvb[h];
  int lk = (h < 2) ? 256 : 64;
  #pragma unroll
  for (int ct = 0; ct < 4; ++ct) {
    int o = ct * 16 + r;
    float bias = kvb[o];
    #pragma unroll
    for (int reg = 0; reg < 4; ++reg) {
      int row = wid * 16 + g * 4 + reg;
      int tg  = tb + row;
      float v = acc[ct][reg] + bias;
      if (o < 32) {
        kb[(size_t)tg * 32 + o] = f2bf_rne(v);
      } else {
        int dd = o - 32;
        int kl = (tg - hb) & (lk - 1);
        int wstart = tg - kl;
        vbT[(size_t)wstart * 32 + dd * lk + kl] = f2bf_rne(v);
      }
    }
  }
}

// ---------------------------------------------------------------------------
// MFMA attention: block = 256 queries, K/V in LDS, bf16 output to cbuf16
// ---------------------------------------------------------------------------
template <int NW, int LK>
__device__ __forceinline__ void attn_v2_body(
    int bid, int head, int head_off, const u16* __restrict__ q,
    const u16* __restrict__ kb, const u16* __restrict__ vbT,
    u16* __restrict__ cbuf16) {
  constexpr int HWIN = H_ / NW;
  constexpr int LQ   = HWIN * HWIN;
  constexpr int BPW  = LQ / 256;          // blocks per window
  constexpr int NCT  = LK / 16;
  constexpr int NST  = LK / 32;
  constexpr int KS   = 40;                // K row stride (u16), 80B
  constexpr int VS   = LK + 8;            // V row stride (u16)
  extern __shared__ __align__(16) u16 alds[];
  u16* klds = alds;                       // [LK][KS]
  u16* vlds = alds + LK * KS;             // [32][VS]
  u16* plds = vlds + 32 * VS;             // 4 waves x 16 x KS (single buffer)
  int tid = threadIdx.x, wid = tid >> 6, lane = tid & 63;
  int g = lane >> 4, c = lane & 15;
  int win  = bid / BPW;
  int n = win / (NW * NW);
  int wrem = win % (NW * NW);
  int wy = wrem / NW, wx = wrem % NW;
  int kstart = head_off + win * LK;

  const u16* kgl = kb  + (size_t)kstart * 32;
  const u16* vgl = vbT + (size_t)kstart * 32;
  for (int ch = tid; ch < LK * 4; ch += 256) {
    int key = ch >> 2, gg = ch & 3;
    *(uint4*)&klds[key * KS + gg * 8] = *(const uint4*)&kgl[ch * 8];
  }
  for (int ch = tid; ch < LK * 4; ch += 256) {   // 32*LK/8 == LK*4
    int d = ch / (LK / 8), pos = ch % (LK / 8);
    *(uint4*)&vlds[d * VS + pos * 8] = *(const uint4*)&vgl[ch * 8];
  }
  __syncthreads();

  u16* pw0 = plds + wid * 16 * KS;
  f32x4 zero4 = {0.f, 0.f, 0.f, 0.f};

  #pragma unroll 1
  for (int tq = 0; tq < 4; ++tq) {
    int tIdx = (bid % BPW) * 16 + wid * 4 + tq;
    int j = tIdx * 16 + c;
    int ih = j / HWIN, iw = j % HWIN;
    int t = (wy * HWIN + ih) * W_ + wx * HWIN + iw;
    bf16x8 qa = *(const bf16x8*)&q[((size_t)n * HW_ + t) * 128 + head * 32 + g * 8];

    f32x4 sacc[NCT];
    #pragma unroll
    for (int ct = 0; ct < NCT; ++ct) {
      bf16x8 kf = *(const bf16x8*)&klds[(ct * 16 + c) * KS + g * 8];
      sacc[ct] = MFMA(qa, kf, zero4);
    }
    #pragma unroll
    for (int reg = 0; reg < 4; ++reg) {
      float mx = -1e30f;
      #pragma unroll
      for (int ct = 0; ct < NCT; ++ct) mx = fmaxf(mx, sacc[ct][reg]);
      mx = fmaxf(mx, __shfl_xor(mx, 1, 64));
      mx = fmaxf(mx, __shfl_xor(mx, 2, 64));
      mx = fmaxf(mx, __shfl_xor(mx, 4, 64));
      mx = fmaxf(mx, __shfl_xor(mx, 8, 64));
      float sm = 0.f;
      #pragma unroll
      for (int ct = 0; ct < NCT; ++ct) {
        float e = __expf((sacc[ct][reg] - mx) * SCALE_);
        sacc[ct][reg] = e;
        sm += e;
      }
      sm += __shfl_xor(sm, 1, 64);
      sm += __shfl_xor(sm, 2, 64);
      sm += __shfl_xor(sm, 4, 64);
      sm += __shfl_xor(sm, 8, 64);
      float inv = 1.0f / sm;
      #pragma unroll
      for (int ct = 0; ct < NCT; ++ct) sacc[ct][reg] *= inv;
    }
    f32x4 oacc[2] = {};
    #pragma unroll
    for (int st = 0; st < NST; ++st) {
      #pragma unroll
      for (int ct2 = 0; ct2 < 2; ++ct2) {
        int ct = st * 2 + ct2;
        #pragma unroll
        for (int reg = 0; reg < 4; ++reg)
          pw0[(g * 4 + reg) * KS + ct2 * 16 + c] = f2bf_rne(sacc[ct][reg]);
      }
      bf16x8 pa = *(const bf16x8*)&pw0[c * KS + g * 8];
      #pragma unroll
      for (int dt = 0; dt < 2; ++dt) {
        bf16x8 vf = *(const bf16x8*)&vlds[(dt * 16 + c) * VS + st * 32 + g * 8];
        oacc[dt] = MFMA(pa, vf, oacc[dt]);
      }
    }
    #pragma unroll
    for (int reg = 0; reg < 4; ++reg) {
      int jo = tIdx * 16 + g * 4 + reg;
      int iho = jo / HWIN, iwo = jo % HWIN;
      int to = (wy * HWIN + iho) * W_ + wx * HWIN + iwo;
      u16* op = cbuf16 + ((size_t)n * HW_ + to) * 128 + head * 32;
      op[c]      = f2bf_rne(oacc[0][reg]);
      op[16 + c] = f2bf_rne(oacc[1][reg]);
    }
  }
}

__global__ __launch_bounds__(256) void attn01_kernel(
    const u16* __restrict__ q, const u16* __restrict__ kb,
    const u16* __restrict__ vbT, u16* __restrict__ cbuf16) {
  int bid = blockIdx.x;
  if (bid < 256) attn_v2_body<1, 256>(bid,       0, 0,    q, kb, vbT, cbuf16);
  else           attn_v2_body<2, 256>(bid - 256, 1, 1024, q, kb, vbT, cbuf16);
}

__global__ __launch_bounds__(256) void attn23_kernel(
    const u16* __restrict__ q, const u16* __restrict__ kb,
    const u16* __restrict__ vbT, u16* __restrict__ cbuf16) {
  int bid = blockIdx.x;
  if (bid < 256) attn_v2_body<4, 64>(bid,       2, 5120, q, kb, vbT, cbuf16);
  else           attn_v2_body<8, 64>(bid - 256, 3, 9216, q, kb, vbT, cbuf16);
}

// ---------------------------------------------------------------------------
// final projection: bf16 input contiguous A-frags + FRAG-ORDER B.
// no LDS, no syncs. fp32 out + bias.
// ---------------------------------------------------------------------------
__global__ __launch_bounds__(256) void proj_mfma_kernel(
    const u16* __restrict__ x16, const u16* __restrict__ wh,
    const u16* __restrict__ wl, const float* __restrict__ b,
    float* __restrict__ out) {
  int tid = threadIdx.x;
  int r0 = blockIdx.x * 64;
  int wid = tid >> 6, lane = tid & 63, r = lane & 15, g = lane >> 4;
  const u16* xr = x16 + (size_t)(r0 + wid * 16 + r) * 128 + g * 8;
  bf16x8 af[4];
  #pragma unroll
  for (int kk = 0; kk < 4; ++kk)
    af[kk] = *(const bf16x8*)&xr[kk * 32];
  int fl8 = lane * 8;
  f32x4 acc[8] = {};
  #pragma unroll
  for (int kk = 0; kk < 4; ++kk) {
    #pragma unroll
    for (int ct = 0; ct < 8; ++ct) {
      int fo = (ct * 4 + kk) * 512 + fl8;
      bf16x8 bh = *(const bf16x8*)&wh[fo];
      bf16x8 bl = *(const bf16x8*)&wl[fo];
      acc[ct] = MFMA(af[kk], bh, acc[ct]);
      acc[ct] = MFMA(af[kk], bl, acc[ct]);
    }
  }
  #pragma unroll
  for (int ct = 0; ct < 8; ++ct) {
    int col = ct * 16 + r;
    #pragma unroll
    for (int reg = 0; reg < 4; ++reg) {
      int row = r0 + wid * 16 + g * 4 + reg;
      out[(size_t)row * 128 + col] = acc[ct][reg] + b[col];
    }
  }
}

// ---------------------------------------------------------------------------
extern "C" void kernel_launch(void* const* d_in, const int* in_sizes, int n_in,
                              void* d_out, int out_size, void* d_ws, size_t ws_size,
                              hipStream_t stream) {
  const float* inp = (const float*)d_in[0];
  const float* nw  = (const float*)d_in[1];
  const float* nb  = (const float*)d_in[2];
  const float* qw  = (const float*)d_in[3];
  const float* qb  = (const float*)d_in[4];
  const float* pw  = (const float*)d_in[29];
  const float* pb  = (const float*)d_in[30];

  float* ws   = (float*)d_ws;
  u16*   qb16 = (u16*)(ws + QB_OFF);
  u16*   yb16 = (u16*)(ws + Y_OFF);
  u16*   kb   = (u16*)(ws + KB_OFF);
  u16*   vbT  = (u16*)(ws + VT_OFF);
  u16*   partb = (u16*)(ws + PART_OFF);       // bf16 partials (8.39M u16)
  u16*   inphT = partb + 8388608;             // [token][c] bf16 (8.39M u16)
  u16*   cbuf16 = partb;                      // aliases partials (dead by then)
  u16*   wsp  = (u16*)(ws + WSP_OFF);
  u16*   whi  = wsp;
  u16*   wlo  = wsp + TOTW;
  u16*   inph = (u16*)(ws + INH_OFF);
  float* scb  = ws + SCB_OFF;

  // 0) prep: input -> inph + inphT (one read); weights -> frag-order bf16
  prep_kernel<<<1024 + TOTW / 256 + 1, 256, 0, stream>>>(
      inp, qw, pw, (const float*)d_in[5], (const float*)d_in[11],
      (const float*)d_in[17], (const float*)d_in[23],
      (const float*)d_in[9], (const float*)d_in[15],
      (const float*)d_in[21], (const float*)d_in[27],
      nw, nb, qb, whi, wlo, inph, inphT, scb);

  // 1) merged convs (no LDS/barriers, frag-order B) + LN-folded Q projection
  convlnq_kernel<<<2048, 256, 0, stream>>>(inph, inphT, whi, wlo, scb,
                                           partb, qb16);

  // 2) reduce bf16 partials + bias -> y bf16 (all heads)
  reduce_kernel<<<6400, 256, 0, stream>>>(partb, (const float*)d_in[6],
                                          (const float*)d_in[12],
                                          (const float*)d_in[18],
                                          (const float*)d_in[24], yb16);

  // 3) fused LN + GELU + KV projection (MFMA, coalesced B, bf16 y)
  LnkvArgs la;
  la.lnw[0] = (const float*)d_in[7];  la.lnb[0] = (const float*)d_in[8];
  la.kvb[0] = (const float*)d_in[10];
  la.lnw[1] = (const float*)d_in[13]; la.lnb[1] = (const float*)d_in[14];
  la.kvb[1] = (const float*)d_in[16];
  la.lnw[2] = (const float*)d_in[19]; la.lnb[2] = (const float*)d_in[20];
  la.kvb[2] = (const float*)d_in[22];
  la.lnw[3] = (const float*)d_in[25]; la.lnb[3] = (const float*)d_in[26];
  la.kvb[3] = (const float*)d_in[28];
  lnkv_mfma_kernel<<<400, 256, 0, stream>>>(yb16, whi + OKV, wlo + OKV, la,
                                            kb, vbT);

  // 4) MFMA attention -> bf16 cbuf16 (partials region, now dead)
  attn01_kernel<<<512, 256, 42496, stream>>>(qb16, kb, vbT, cbuf16);
  attn23_kernel<<<512, 256, 14848, stream>>>(qb16, kb, vbT, cbuf16);

  // 5) final projection: bf16 in, coalesced frag B, fp32 out to d_out
  proj_mfma_kernel<<<1024, 256, 0, stream>>>(cbuf16, whi + OPW, wlo + OPW, pb,
                                             (float*)d_out);
}

// Round 22
// 107.363 us; speedup vs baseline: 1.0723x; 1.0723x over previous
//
#include <hip/hip_runtime.h>
#include <math.h>

#define N_   4
#define C_   128
#define H_   128
#define W_   128
#define HW_  16384
#define SCALE_ 0.17677669529663687f   // 32^-0.5

typedef unsigned short u16;
typedef unsigned int   u32;
typedef __bf16 bf16x8 __attribute__((ext_vector_type(8)));
typedef float  f32x4  __attribute__((ext_vector_type(4)));

#define MFMA(a, b, c) __builtin_amdgcn_mfma_f32_16x16x32_bf16((a), (b), (c), 0, 0, 0)

// ---- ws float offsets -------------------------------------------------------
#define QB_OFF   0            // 4,194,304 floats (8,388,608 u16 bf16 q)
#define KB_OFF   5832704      //   409,600 floats (819,200 u16 bf16 K)
#define VT_OFF   6242304      //   409,600 floats (819,200 u16 bf16 V^T)
#define PART_OFF 6651904      // 8,388,608 floats:
                              //   [0..4.19M): bf16 partials (8.39M u16); cbuf16 aliases
                              //   [4.19M..8.39M): inphT (8.39M u16, [token][c])
#define WSP_OFF  15040512     //   868,352 floats (2 x 868,352 u16 hi+lo)
#define INH_OFF  15908864     // 4,194,304 floats (8,388,608 u16 bf16 input [c][t])
#define SCB_OFF  20103168     //       256 floats (S[128], cb[128])
// total 20,103,424 floats = 80.4 MB

// split-weight region offsets (u16 units, within hi or lo half)
// OQW/OPW/OKV in MFMA FRAGMENT ORDER; conv heads (OS1..OS4) in per-seg
// FRAGMENT ORDER: dst = base + seg*16384 + ((ct*8+kt)*64 + lane)*8 + e
#define OQW 0
#define OPW 16384
#define OS1 32768
#define OS2 557056
#define OS3 688128
#define OS4 819200
#define OKV 851968
#define TOTW 868352

#define GS  520    // A-LDS kgroup stride (lnkv), u16

// ---------------------------------------------------------------------------
__device__ __forceinline__ u16 f2bf_rne(float x) {
  unsigned u = __float_as_uint(x);
  return (u16)((u + 0x7FFFu + ((u >> 16) & 1u)) >> 16);
}
__device__ __forceinline__ float bf2f(u16 x) {
  return __uint_as_float((u32)x << 16);
}
__device__ __forceinline__ void split2(float v, u16& h, u16& l) {
  unsigned u = __float_as_uint(v);
  unsigned hb = (u + 0x7FFFu + ((u >> 16) & 1u)) & 0xFFFF0000u;
  h = (u16)(hb >> 16);
  float lf = v - __uint_as_float(hb);
  l = f2bf_rne(lf);
}

// ---------------------------------------------------------------------------
// prep: [bid<1024]       input fp32 tile -> inph bf16 [c][t] AND inphT [t][c]
//       [1024..+3392)    weights fp32 -> bf16 hi/lo, fragment orders
//       [last block]     S[o], cb[o]
// ---------------------------------------------------------------------------
__global__ __launch_bounds__(256) void prep_kernel(
    const float* __restrict__ inp, const float* __restrict__ qw,
    const float* __restrict__ pw, const float* __restrict__ s1,
    const float* __restrict__ s2, const float* __restrict__ s3,
    const float* __restrict__ s4, const float* __restrict__ kv1,
    const float* __restrict__ kv2, const float* __restrict__ kv3,
    const float* __restrict__ kv4, const float* __restrict__ nw,
    const float* __restrict__ nb, const float* __restrict__ qb,
    u16* __restrict__ hi, u16* __restrict__ lo, u16* __restrict__ inph,
    u16* __restrict__ inphT, float* __restrict__ scb) {
  __shared__ float tls[64 * 133];
  int bid = blockIdx.x, tid = threadIdx.x;
  if (bid < 1024) {
    int n = bid >> 8, t0 = (bid & 255) * 64;
    const float* xb = inp + (size_t)n * C_ * HW_ + t0;
    u16* ihb = inph + (size_t)n * C_ * HW_ + t0;
    #pragma unroll
    for (int it = 0; it < 8; ++it) {
      int u = it * 256 + tid;                 // 2048 float4 units
      int c = u >> 4, tokg = u & 15;
      float4 v = *(const float4*)&xb[(size_t)c * HW_ + tokg * 4];
      ushort4 h4;
      h4.x = f2bf_rne(v.x); h4.y = f2bf_rne(v.y);
      h4.z = f2bf_rne(v.z); h4.w = f2bf_rne(v.w);
      *(ushort4*)&ihb[(size_t)c * HW_ + tokg * 4] = h4;
      tls[(tokg * 4 + 0) * 133 + c] = v.x;
      tls[(tokg * 4 + 1) * 133 + c] = v.y;
      tls[(tokg * 4 + 2) * 133 + c] = v.z;
      tls[(tokg * 4 + 3) * 133 + c] = v.w;
    }
    __syncthreads();
    #pragma unroll
    for (int it = 0; it < 4; ++it) {
      int u = it * 256 + tid;                 // 1024 units
      int tok = u >> 4, cg = u & 15;
      union { u16 e[8]; uint4 q; } cv;
      #pragma unroll
      for (int e = 0; e < 8; ++e)
        cv.e[e] = f2bf_rne(tls[tok * 133 + cg * 8 + e]);
      *(uint4*)&inphT[((size_t)(n * HW_ + t0 + tok)) * 128 + cg * 8] = cv.q;
    }
  } else if (bid < 1024 + TOTW / 256) {
    int idx = (bid - 1024) * 256 + tid;       // < TOTW (source-linear)
    const float* src; int off;
    float mul = 1.0f;
    int dst = idx;
    if (idx < OPW) {                       // qw: 128x128 -> frag order
      src = qw; off = idx; mul = nw[idx & 127];
      int o = idx >> 7, k = idx & 127;
      int ct = o >> 4, r = o & 15, kk = k >> 5, g = (k >> 3) & 3, e = k & 7;
      dst = OQW + ((ct * 4 + kk) * 64 + g * 16 + r) * 8 + e;
    } else if (idx < OS1) {                // pw: 128x128 -> frag order
      src = pw; off = idx - OPW;
      int o = off >> 7, k = off & 127;
      int ct = o >> 4, r = o & 15, kk = k >> 5, g = (k >> 3) & 3, e = k & 7;
      dst = OPW + ((ct * 4 + kk) * 64 + g * 16 + r) * 8 + e;
    } else if (idx < OS2) {                // conv1: 64x8192 -> per-seg frag
      src = s1; off = idx - OS1;
      int o = off >> 13, k = off & 8191;
      int seg = k >> 8, kt = (k >> 5) & 7, g = (k >> 3) & 3, e = k & 7;
      dst = OS1 + seg * 16384 +
            (((o >> 4) * 8 + kt) * 64 + g * 16 + (o & 15)) * 8 + e;
    } else if (idx < OS3) {                // conv2: 64x2048 -> per-seg frag
      src = s2; off = idx - OS2;
      int o = off >> 11, k = off & 2047;
      int seg = k >> 8, kt = (k >> 5) & 7, g = (k >> 3) & 3, e = k & 7;
      dst = OS2 + seg * 16384 +
            (((o >> 4) * 8 + kt) * 64 + g * 16 + (o & 15)) * 8 + e;
    } else if (idx < OS4) {                // conv3: 64x2048 -> per-seg frag
      src = s3; off = idx - OS3;
      int o = off >> 11, k = off & 2047;
      int seg = k >> 8, kt = (k >> 5) & 7, g = (k >> 3) & 3, e = k & 7;
      dst = OS3 + seg * 16384 +
            (((o >> 4) * 8 + kt) * 64 + g * 16 + (o & 15)) * 8 + e;
    } else if (idx < OKV) {                // conv4: 64x512 -> per-seg frag
      src = s4; off = idx - OS4;
      int o = off >> 9, k = off & 511;
      int seg = k >> 8, kt = (k >> 5) & 7, g = (k >> 3) & 3, e = k & 7;
      dst = OS4 + seg * 16384 +
            (((o >> 4) * 8 + kt) * 64 + g * 16 + (o & 15)) * 8 + e;
    } else {                               // kv: 4 x 64x64 -> frag order
      int j = idx - OKV;
      int h = j >> 12; int o2 = j & 4095;
      src = (h == 0) ? kv1 : (h == 1) ? kv2 : (h == 2) ? kv3 : kv4;
      off = o2;
      int o = o2 >> 6, k = o2 & 63;
      int ct = o >> 4, r = o & 15, kk = k >> 5, g = (k >> 3) & 3, e = k & 7;
      dst = OKV + h * 4096 + ((ct * 2 + kk) * 64 + g * 16 + r) * 8 + e;
    }
    u16 h, l; split2(src[off] * mul, h, l);
    hi[dst] = h; lo[dst] = l;
  } else {
    int o = tid;
    if (o < 128) {
      float S = 0.f, cbv = qb[o];
      const float* wr = qw + o * 128;
      for (int c = 0; c < 128; ++c) {
        float w = wr[c];
        S   += w * nw[c];
        cbv += w * nb[c];
      }
      scb[o]       = S;
      scb[128 + o] = cbv;
    }
  }
}

// ---------------------------------------------------------------------------
// LN-folded Q projection, contiguous A-frags from inphT, FRAG-ORDER B loads
// ---------------------------------------------------------------------------
__device__ __forceinline__ void lnqT_body(
    int bid, const u16* __restrict__ inphT, const u16* __restrict__ wh,
    const u16* __restrict__ wl, const float* __restrict__ scb,
    u16* __restrict__ q) {
  int tid = threadIdx.x;
  int n = bid >> 8, t0 = (bid & 255) * 64;
  int wid = tid >> 6, lane = tid & 63, r = lane & 15, g = lane >> 4;
  const u16* xr = inphT + (size_t)(n * HW_ + t0 + wid * 16 + r) * 128 + g * 8;

  bf16x8 af[4];
  float s = 0.f, s2 = 0.f;
  #pragma unroll
  for (int kk = 0; kk < 4; ++kk) {
    union { uint4 u; u16 e[8]; bf16x8 b; } cv;
    cv.u = *(const uint4*)&xr[kk * 32];
    #pragma unroll
    for (int e = 0; e < 8; ++e) { float f = bf2f(cv.e[e]); s += f; s2 += f * f; }
    af[kk] = cv.b;
  }
  s  += __shfl_xor(s, 16, 64);  s  += __shfl_xor(s, 32, 64);
  s2 += __shfl_xor(s2, 16, 64); s2 += __shfl_xor(s2, 32, 64);
  float mu = s * (1.0f / 128.0f);
  float var = s2 * (1.0f / 128.0f) - mu * mu;
  float rs = rsqrtf(var + 1e-5f);

  int fl8 = lane * 8;                      // frag-order per-lane offset
  f32x4 acc[8] = {};
  #pragma unroll
  for (int kk = 0; kk < 4; ++kk) {
    #pragma unroll
    for (int ct = 0; ct < 8; ++ct) {
      int fo = (ct * 4 + kk) * 512 + fl8;
      bf16x8 bh = *(const bf16x8*)&wh[fo];
      bf16x8 bl = *(const bf16x8*)&wl[fo];
      acc[ct] = MFMA(af[kk], bh, acc[ct]);
      acc[ct] = MFMA(af[kk], bl, acc[ct]);
    }
  }
  #pragma unroll
  for (int reg = 0; reg < 4; ++reg) {
    float mur = __shfl(mu, g * 4 + reg, 64);
    float rsr = __shfl(rs, g * 4 + reg, 64);
    int row = wid * 16 + g * 4 + reg;
    #pragma unroll
    for (int ct = 0; ct < 8; ++ct) {
      int col = ct * 16 + r;
      float val = rsr * (acc[ct][reg] - mur * scb[col]) + scb[128 + col];
      q[((size_t)n * HW_ + t0 + row) * 128 + col] = f2bf_rne(val);
    }
  }
}

// ---------------------------------------------------------------------------
// conv-as-GEMM: BM=128, KSEG=256 (NT=8). NO LDS, NO barriers — A-frags direct,
// B-frags per-seg FRAG-ORDER (coalesced). Partials stored BF16.
// ---------------------------------------------------------------------------
template <int P, int NW, int SEG>
__device__ __forceinline__ void conv_body(
    int mblk, int seg, const u16* __restrict__ inph,
    const u16* __restrict__ wh, u16* __restrict__ dst) {
  constexpr int K    = 128 * P * P;
  constexpr int KSEG = K / SEG;              // 256 everywhere
  constexpr int NT   = KSEG / 32;            // 8
  constexpr int HWIN = H_ / NW;
  constexpr int G    = HWIN / P;
  constexpr int L    = G * G;
  constexpr int M    = 4 * NW * NW * L;
  constexpr int LGL  = (L == 256) ? 8 : 6;
  constexpr int LGG  = (G == 16) ? 4 : 3;
  constexpr int LGNW = (NW == 8) ? 3 : (NW == 4) ? 2 : (NW == 2) ? 1 : 0;
  constexpr int LGP  = (P == 8) ? 3 : (P == 4) ? 2 : 1;
  constexpr int LGP2 = 2 * LGP;
  int tid = threadIdx.x, wid = tid >> 6, lane = tid & 63;
  int r = lane & 15, g = lane >> 4;
  int t0 = mblk * 128;
  int kbase = seg * KSEG;

  size_t rbase[2];
  #pragma unroll
  for (int mrep = 0; mrep < 2; ++mrep) {
    int tglob = t0 + wid * 32 + mrep * 16 + r;
    int bwin = tglob >> LGL;
    int loc  = tglob & (L - 1);
    int n    = bwin >> (2 * LGNW);
    int wrem = bwin & (NW * NW - 1);
    int wy = wrem >> LGNW, wx = wrem & (NW - 1);
    int oh = loc >> LGG,   ow = loc & (G - 1);
    rbase[mrep] = (size_t)n * C_ * HW_ + (size_t)(wy * HWIN + oh * P) * W_ +
                  wx * HWIN + ow * P;
  }
  const u16* wf = wh + (size_t)seg * 16384 + (size_t)lane * 8;

  f32x4 acc[2][4] = {};

  #pragma unroll
  for (int kt = 0; kt < NT; ++kt) {
    int k0 = kbase + kt * 32 + g * 8;
    int ci = k0 >> LGP2;
    int wp = k0 & (P * P - 1);
    union { uint4 u; bf16x8 b; } a0, a1;
    if constexpr (P == 8) {
      size_t koff = (size_t)ci * HW_ + (wp >> 3) * W_;
      a0.u = *(const uint4*)&inph[rbase[0] + koff];
      a1.u = *(const uint4*)&inph[rbase[1] + koff];
    } else if constexpr (P == 4) {
      int kh = wp >> 2;
      size_t b0 = rbase[0] + (size_t)ci * HW_;
      size_t b1 = rbase[1] + (size_t)ci * HW_;
      uint2 l0 = *(const uint2*)&inph[b0 + kh * W_];
      uint2 h0 = *(const uint2*)&inph[b0 + (kh + 1) * W_];
      uint2 l1 = *(const uint2*)&inph[b1 + kh * W_];
      uint2 h1 = *(const uint2*)&inph[b1 + (kh + 1) * W_];
      a0.u = make_uint4(l0.x, l0.y, h0.x, h0.y);
      a1.u = make_uint4(l1.x, l1.y, h1.x, h1.y);
    } else {  // P == 2
      size_t b0 = rbase[0] + (size_t)ci * HW_;
      size_t b1 = rbase[1] + (size_t)ci * HW_;
      a0.u = make_uint4(*(const u32*)&inph[b0], *(const u32*)&inph[b0 + W_],
                        *(const u32*)&inph[b0 + HW_], *(const u32*)&inph[b0 + HW_ + W_]);
      a1.u = make_uint4(*(const u32*)&inph[b1], *(const u32*)&inph[b1 + W_],
                        *(const u32*)&inph[b1 + HW_], *(const u32*)&inph[b1 + HW_ + W_]);
    }
    #pragma unroll
    for (int ct = 0; ct < 4; ++ct) {
      bf16x8 bh = *(const bf16x8*)&wf[(ct * 8 + kt) * 512];
      acc[0][ct] = MFMA(a0.b, bh, acc[0][ct]);
      acc[1][ct] = MFMA(a1.b, bh, acc[1][ct]);
    }
  }
  #pragma unroll
  for (int mrep = 0; mrep < 2; ++mrep) {
    #pragma unroll
    for (int ct = 0; ct < 4; ++ct) {
      int o = ct * 16 + r;
      #pragma unroll
      for (int reg = 0; reg < 4; ++reg) {
        int row = t0 + wid * 32 + mrep * 16 + g * 4 + reg;
        dst[((size_t)seg * M + row) * 64 + o] = f2bf_rne(acc[mrep][ct][reg]);
      }
    }
  }
}

// ---------------------------------------------------------------------------
// merged: [bid<1024] convs (no LDS, no barriers) ; [bid>=1024] LN-folded Q
// ---------------------------------------------------------------------------
__global__ __launch_bounds__(256) void convlnq_kernel(
    const u16* __restrict__ inph, const u16* __restrict__ inphT,
    const u16* __restrict__ whi, const u16* __restrict__ wlo,
    const float* __restrict__ scb, u16* __restrict__ part,
    u16* __restrict__ q) {
  int bid = blockIdx.x;
  if (bid < 256) {            // head1: 8 mblk x 32 seg
    conv_body<8, 1, 32>(bid >> 5, bid & 31, inph, whi + OS1, part);
  } else if (bid < 512) {     // head2: 32 mblk x 8 seg
    int lb = bid - 256;
    conv_body<4, 2, 8>(lb >> 3, lb & 7, inph, whi + OS2, part + 2097152);
  } else if (bid < 768) {     // head3: 32 mblk x 8 seg
    int lb = bid - 512;
    conv_body<4, 4, 8>(lb >> 3, lb & 7, inph, whi + OS3, part + 4194304);
  } else if (bid < 1024) {    // head4: 128 mblk x 2 seg
    int lb = bid - 768;
    conv_body<2, 8, 2>(lb >> 1, lb & 1, inph, whi + OS4, part + 6291456);
  } else {                    // lnq: 1024 blocks
    lnqT_body(bid - 1024, inphT, whi + OQW, wlo + OQW, scb, q);
  }
}

// ---------------------------------------------------------------------------
// fused: partial-reduce(+conv bias) + LN(64) + exact GELU + KV proj (MFMA).
// 64 tokens/block, 400 blocks. K out bf16 [token][32]; V out bf16 [d][k].
// ---------------------------------------------------------------------------
struct LnkvArgs { const float* lnw[4]; const float* lnb[4];
                  const float* kvb[4]; const float* cb[4]; };

__global__ __launch_bounds__(256) void lnkv_mfma_kernel(
    const u16* __restrict__ part, const u16* __restrict__ kvwh,
    const u16* __restrict__ kvwl, LnkvArgs a,
    u16* __restrict__ kb, u16* __restrict__ vbT) {
  __shared__ float ych[64 * 65];
  __shared__ __align__(16) u16 ash[8 * GS];
  __shared__ __align__(16) u16 asl[8 * GS];
  int bid = blockIdx.x, tid = threadIdx.x;
  int tb = bid * 64;
  int h  = (tb < 1024) ? 0 : (tb < 5120) ? 1 : (tb < 9216) ? 2 : 3;
  int hb = (h == 0) ? 0 : (h == 1) ? 1024 : (h == 2) ? 5120 : 9216;
  int u0 = tb - hb;
  const u16* ph; int M, SEGc;
  if (h == 0)      { ph = part;           M = 1024;  SEGc = 32; }
  else if (h == 1) { ph = part + 2097152; M = 4096;  SEGc = 8;  }
  else if (h == 2) { ph = part + 4194304; M = 4096;  SEGc = 8;  }
  else             { ph = part + 6291456; M = 16384; SEGc = 2;  }
  const float* cb = a.cb[h];

  // fused partial reduction: each thread owns 2 uint4 positions (16 values)
  {
    float av[2][8];
    #pragma unroll
    for (int it = 0; it < 2; ++it) {
      int i8 = it * 256 + tid;              // 512 uint4 units
      int cg = i8 & 7;
      #pragma unroll
      for (int e = 0; e < 8; ++e) av[it][e] = cb[cg * 8 + e];
    }
    for (int sg = 0; sg < SEGc; ++sg) {
      #pragma unroll
      for (int it = 0; it < 2; ++it) {
        int i8 = it * 256 + tid;
        int row = i8 >> 3, cg = i8 & 7;
        union { uint4 u; u16 e[8]; } cv;
        cv.u = *(const uint4*)&ph[((size_t)sg * M + u0 + row) * 64 + cg * 8];
        #pragma unroll
        for (int e = 0; e < 8; ++e) av[it][e] += bf2f(cv.e[e]);
      }
    }
    #pragma unroll
    for (int it = 0; it < 2; ++it) {
      int i8 = it * 256 + tid;
      int row = i8 >> 3, cg = i8 & 7;
      #pragma unroll
      for (int e = 0; e < 8; ++e)
        ych[row * 65 + cg * 8 + e] = av[it][e];
    }
  }
  __syncthreads();
  {
    int tt = tid >> 2, p = tid & 3;
    const float* xr = &ych[tt * 65 + p * 16];
    float s = 0.f, s2 = 0.f;
    #pragma unroll
    for (int i = 0; i < 16; ++i) { float v = xr[i]; s += v; s2 += v * v; }
    s  += __shfl_xor(s, 1, 64);  s  += __shfl_xor(s, 2, 64);
    s2 += __shfl_xor(s2, 1, 64); s2 += __shfl_xor(s2, 2, 64);
    float mean = s * (1.0f / 64.0f);
    float var  = s2 * (1.0f / 64.0f) - mean * mean;
    float rstd = rsqrtf(var + 1e-5f);
    const float* lnw = a.lnw[h];
    const float* lnb = a.lnb[h];
    #pragma unroll
    for (int i = 0; i < 16; ++i) {
      int ch = p * 16 + i;
      float xn = (xr[i] - mean) * rstd * lnw[ch] + lnb[ch];
      float gg = 0.5f * xn * (1.0f + erff(xn * 0.70710678118654752f));
      u16 hh, ll; split2(gg, hh, ll);
      int o = (ch >> 3) * GS + tt * 8 + (ch & 7);
      ash[o] = hh; asl[o] = ll;
    }
  }
  __syncthreads();
  int wid = tid >> 6, lane = tid & 63, r = lane & 15, g = lane >> 4;
  const u16* wbh = kvwh + h * 4096;
  const u16* wbl = kvwl + h * 4096;
  int fl8 = lane * 8;
  f32x4 acc[4] = {};
  #pragma unroll
  for (int kk = 0; kk < 2; ++kk) {
    bf16x8 ah = *(const bf16x8*)&ash[(kk * 4 + g) * GS + (wid * 16 + r) * 8];
    bf16x8 al = *(const bf16x8*)&asl[(kk * 4 + g) * GS + (wid * 16 + r) * 8];
    #pragma unroll
    for (int ct = 0; ct < 4; ++ct) {
      int fo = (ct * 2 + kk) * 512 + fl8;
      bf16x8 bh = *(const bf16x8*)&wbh[fo];
      bf16x8 bl = *(const bf16x8*)&wbl[fo];
      acc[ct] = MFMA(ah, bh, acc[ct]);
      acc[ct] = MFMA(ah, bl, acc[ct]);
      acc[ct] = MFMA(al, bh, acc[ct]);
    }
  }
  const float* kvb = a.kvb[h];
  int lk = (h < 2) ? 256 : 64;
  #pragma unroll
  for (int ct = 0; ct < 4; ++ct) {
    int o = ct * 16 + r;
    float bias = kvb[o];
    #pragma unroll
    for (int reg = 0; reg < 4; ++reg) {
      int row = wid * 16 + g * 4 + reg;
      int tg  = tb + row;
      float v = acc[ct][reg] + bias;
      if (o < 32) {
        kb[(size_t)tg * 32 + o] = f2bf_rne(v);
      } else {
        int dd = o - 32;
        int kl = (tg - hb) & (lk - 1);
        int wstart = tg - kl;
        vbT[(size_t)wstart * 32 + dd * lk + kl] = f2bf_rne(v);
      }
    }
  }
}

// ---------------------------------------------------------------------------
// MFMA attention: block = 256 queries, K/V in LDS, bf16 output to cbuf16.
// ALL HEADS in one launch (no inter-head dependency -> overlap).
// ---------------------------------------------------------------------------
template <int NW, int LK>
__device__ __forceinline__ void attn_v2_body(
    int bid, int head, int head_off, const u16* __restrict__ q,
    const u16* __restrict__ kb, const u16* __restrict__ vbT,
    u16* __restrict__ cbuf16) {
  constexpr int HWIN = H_ / NW;
  constexpr int LQ   = HWIN * HWIN;
  constexpr int BPW  = LQ / 256;          // blocks per window
  constexpr int NCT  = LK / 16;
  constexpr int NST  = LK / 32;
  constexpr int KS   = 40;                // K row stride (u16), 80B
  constexpr int VS   = LK + 8;            // V row stride (u16)
  extern __shared__ __align__(16) u16 alds[];
  u16* klds = alds;                       // [LK][KS]
  u16* vlds = alds + LK * KS;             // [32][VS]
  u16* plds = vlds + 32 * VS;             // 4 waves x 16 x KS (single buffer)
  int tid = threadIdx.x, wid = tid >> 6, lane = tid & 63;
  int g = lane >> 4, c = lane & 15;
  int win  = bid / BPW;
  int n = win / (NW * NW);
  int wrem = win % (NW * NW);
  int wy = wrem / NW, wx = wrem % NW;
  int kstart = head_off + win * LK;

  const u16* kgl = kb  + (size_t)kstart * 32;
  const u16* vgl = vbT + (size_t)kstart * 32;
  for (int ch = tid; ch < LK * 4; ch += 256) {
    int key = ch >> 2, gg = ch & 3;
    *(uint4*)&klds[key * KS + gg * 8] = *(const uint4*)&kgl[ch * 8];
  }
  for (int ch = tid; ch < LK * 4; ch += 256) {   // 32*LK/8 == LK*4
    int d = ch / (LK / 8), pos = ch % (LK / 8);
    *(uint4*)&vlds[d * VS + pos * 8] = *(const uint4*)&vgl[ch * 8];
  }
  __syncthreads();

  u16* pw0 = plds + wid * 16 * KS;
  f32x4 zero4 = {0.f, 0.f, 0.f, 0.f};

  #pragma unroll 1
  for (int tq = 0; tq < 4; ++tq) {
    int tIdx = (bid % BPW) * 16 + wid * 4 + tq;
    int j = tIdx * 16 + c;
    int ih = j / HWIN, iw = j % HWIN;
    int t = (wy * HWIN + ih) * W_ + wx * HWIN + iw;
    bf16x8 qa = *(const bf16x8*)&q[((size_t)n * HW_ + t) * 128 + head * 32 + g * 8];

    f32x4 sacc[NCT];
    #pragma unroll
    for (int ct = 0; ct < NCT; ++ct) {
      bf16x8 kf = *(const bf16x8*)&klds[(ct * 16 + c) * KS + g * 8];
      sacc[ct] = MFMA(qa, kf, zero4);
    }
    #pragma unroll
    for (int reg = 0; reg < 4; ++reg) {
      float mx = -1e30f;
      #pragma unroll
      for (int ct = 0; ct < NCT; ++ct) mx = fmaxf(mx, sacc[ct][reg]);
      mx = fmaxf(mx, __shfl_xor(mx, 1, 64));
      mx = fmaxf(mx, __shfl_xor(mx, 2, 64));
      mx = fmaxf(mx, __shfl_xor(mx, 4, 64));
      mx = fmaxf(mx, __shfl_xor(mx, 8, 64));
      float sm = 0.f;
      #pragma unroll
      for (int ct = 0; ct < NCT; ++ct) {
        float e = __expf((sacc[ct][reg] - mx) * SCALE_);
        sacc[ct][reg] = e;
        sm += e;
      }
      sm += __shfl_xor(sm, 1, 64);
      sm += __shfl_xor(sm, 2, 64);
      sm += __shfl_xor(sm, 4, 64);
      sm += __shfl_xor(sm, 8, 64);
      float inv = 1.0f / sm;
      #pragma unroll
      for (int ct = 0; ct < NCT; ++ct) sacc[ct][reg] *= inv;
    }
    f32x4 oacc[2] = {};
    #pragma unroll
    for (int st = 0; st < NST; ++st) {
      #pragma unroll
      for (int ct2 = 0; ct2 < 2; ++ct2) {
        int ct = st * 2 + ct2;
        #pragma unroll
        for (int reg = 0; reg < 4; ++reg)
          pw0[(g * 4 + reg) * KS + ct2 * 16 + c] = f2bf_rne(sacc[ct][reg]);
      }
      bf16x8 pa = *(const bf16x8*)&pw0[c * KS + g * 8];
      #pragma unroll
      for (int dt = 0; dt < 2; ++dt) {
        bf16x8 vf = *(const bf16x8*)&vlds[(dt * 16 + c) * VS + st * 32 + g * 8];
        oacc[dt] = MFMA(pa, vf, oacc[dt]);
      }
    }
    #pragma unroll
    for (int reg = 0; reg < 4; ++reg) {
      int jo = tIdx * 16 + g * 4 + reg;
      int iho = jo / HWIN, iwo = jo % HWIN;
      int to = (wy * HWIN + iho) * W_ + wx * HWIN + iwo;
      u16* op = cbuf16 + ((size_t)n * HW_ + to) * 128 + head * 32;
      op[c]      = f2bf_rne(oacc[0][reg]);
      op[16 + c] = f2bf_rne(oacc[1][reg]);
    }
  }
}

__global__ __launch_bounds__(256) void attn_kernel(
    const u16* __restrict__ q, const u16* __restrict__ kb,
    const u16* __restrict__ vbT, u16* __restrict__ cbuf16) {
  int bid = blockIdx.x;
  if      (bid < 256)  attn_v2_body<1, 256>(bid,       0, 0,    q, kb, vbT, cbuf16);
  else if (bid < 512)  attn_v2_body<2, 256>(bid - 256, 1, 1024, q, kb, vbT, cbuf16);
  else if (bid < 768)  attn_v2_body<4, 64 >(bid - 512, 2, 5120, q, kb, vbT, cbuf16);
  else                 attn_v2_body<8, 64 >(bid - 768, 3, 9216, q, kb, vbT, cbuf16);
}

// ---------------------------------------------------------------------------
// final projection: bf16 input contiguous A-frags + FRAG-ORDER B.
// no LDS, no syncs. fp32 out + bias.
// ---------------------------------------------------------------------------
__global__ __launch_bounds__(256) void proj_mfma_kernel(
    const u16* __restrict__ x16, const u16* __restrict__ wh,
    const u16* __restrict__ wl, const float* __restrict__ b,
    float* __restrict__ out) {
  int tid = threadIdx.x;
  int r0 = blockIdx.x * 64;
  int wid = tid >> 6, lane = tid & 63, r = lane & 15, g = lane >> 4;
  const u16* xr = x16 + (size_t)(r0 + wid * 16 + r) * 128 + g * 8;
  bf16x8 af[4];
  #pragma unroll
  for (int kk = 0; kk < 4; ++kk)
    af[kk] = *(const bf16x8*)&xr[kk * 32];
  int fl8 = lane * 8;
  f32x4 acc[8] = {};
  #pragma unroll
  for (int kk = 0; kk < 4; ++kk) {
    #pragma unroll
    for (int ct = 0; ct < 8; ++ct) {
      int fo = (ct * 4 + kk) * 512 + fl8;
      bf16x8 bh = *(const bf16x8*)&wh[fo];
      bf16x8 bl = *(const bf16x8*)&wl[fo];
      acc[ct] = MFMA(af[kk], bh, acc[ct]);
      acc[ct] = MFMA(af[kk], bl, acc[ct]);
    }
  }
  #pragma unroll
  for (int ct = 0; ct < 8; ++ct) {
    int col = ct * 16 + r;
    #pragma unroll
    for (int reg = 0; reg < 4; ++reg) {
      int row = r0 + wid * 16 + g * 4 + reg;
      out[(size_t)row * 128 + col] = acc[ct][reg] + b[col];
    }
  }
}

// ---------------------------------------------------------------------------
extern "C" void kernel_launch(void* const* d_in, const int* in_sizes, int n_in,
                              void* d_out, int out_size, void* d_ws, size_t ws_size,
                              hipStream_t stream) {
  const float* inp = (const float*)d_in[0];
  const float* nw  = (const float*)d_in[1];
  const float* nb  = (const float*)d_in[2];
  const float* qw  = (const float*)d_in[3];
  const float* qb  = (const float*)d_in[4];
  const float* pw  = (const float*)d_in[29];
  const float* pb  = (const float*)d_in[30];

  float* ws   = (float*)d_ws;
  u16*   qb16 = (u16*)(ws + QB_OFF);
  u16*   kb   = (u16*)(ws + KB_OFF);
  u16*   vbT  = (u16*)(ws + VT_OFF);
  u16*   partb = (u16*)(ws + PART_OFF);       // bf16 partials (8.39M u16)
  u16*   inphT = partb + 8388608;             // [token][c] bf16 (8.39M u16)
  u16*   cbuf16 = partb;                      // aliases partials (dead by then)
  u16*   wsp  = (u16*)(ws + WSP_OFF);
  u16*   whi  = wsp;
  u16*   wlo  = wsp + TOTW;
  u16*   inph = (u16*)(ws + INH_OFF);
  float* scb  = ws + SCB_OFF;

  // 0) prep: input -> inph + inphT (one read); weights -> frag-order bf16
  prep_kernel<<<1024 + TOTW / 256 + 1, 256, 0, stream>>>(
      inp, qw, pw, (const float*)d_in[5], (const float*)d_in[11],
      (const float*)d_in[17], (const float*)d_in[23],
      (const float*)d_in[9], (const float*)d_in[15],
      (const float*)d_in[21], (const float*)d_in[27],
      nw, nb, qb, whi, wlo, inph, inphT, scb);

  // 1) merged convs (no LDS/barriers, frag-order B) + LN-folded Q projection
  convlnq_kernel<<<2048, 256, 0, stream>>>(inph, inphT, whi, wlo, scb,
                                           partb, qb16);

  // 2) fused partial-reduce + LN + GELU + KV projection (MFMA)
  LnkvArgs la;
  la.lnw[0] = (const float*)d_in[7];  la.lnb[0] = (const float*)d_in[8];
  la.kvb[0] = (const float*)d_in[10]; la.cb[0]  = (const float*)d_in[6];
  la.lnw[1] = (const float*)d_in[13]; la.lnb[1] = (const float*)d_in[14];
  la.kvb[1] = (const float*)d_in[16]; la.cb[1]  = (const float*)d_in[12];
  la.lnw[2] = (const float*)d_in[19]; la.lnb[2] = (const float*)d_in[20];
  la.kvb[2] = (const float*)d_in[22]; la.cb[2]  = (const float*)d_in[18];
  la.lnw[3] = (const float*)d_in[25]; la.lnb[3] = (const float*)d_in[26];
  la.kvb[3] = (const float*)d_in[28]; la.cb[3]  = (const float*)d_in[24];
  lnkv_mfma_kernel<<<400, 256, 0, stream>>>(partb, whi + OKV, wlo + OKV, la,
                                            kb, vbT);

  // 3) MFMA attention, all heads one launch (LDS sized for LK=256: 42496 B)
  attn_kernel<<<1024, 256, 42496, stream>>>(qb16, kb, vbT, cbuf16);

  // 4) final projection: bf16 in, coalesced frag B, fp32 out to d_out
  proj_mfma_kernel<<<1024, 256, 0, stream>>>(cbuf16, whi + OPW, wlo + OPW, pb,
                                             (float*)d_out);
}